// Round 5
// baseline (416.772 us; speedup 1.0000x reference)
//
#include <hip/hip_runtime.h>
#include <hip/hip_bf16.h>
#include <math.h>

#define NN 200000
#define NE 200000

typedef __attribute__((ext_vector_type(8))) short bf16x8;
typedef __attribute__((ext_vector_type(4))) float f32x4;

__device__ __forceinline__ float sigm(float x) { return 1.0f / (1.0f + expf(-x)); }

__device__ __forceinline__ ushort f2b(float x) {
    union { __hip_bfloat16 b; ushort u; } v;
    v.b = __float2bfloat16(x);
    return v.u;
}
__device__ __forceinline__ float b2f(ushort u) {
    return __uint_as_float(((unsigned)u) << 16);
}
__device__ __forceinline__ ushort4 cvt4(float4 v) {
    ushort4 u; u.x = f2b(v.x); u.y = f2b(v.y); u.z = f2b(v.z); u.w = f2b(v.w);
    return u;
}
__device__ __forceinline__ void gload_lds16(const ushort* g, ushort* l) {
    __builtin_amdgcn_global_load_lds(
        (const __attribute__((address_space(1))) unsigned int*)g,
        (__attribute__((address_space(3))) unsigned int*)l, 16, 0, 0);
}

#define MFMA16(a, b, c) __builtin_amdgcn_mfma_f32_16x16x32_bf16((a), (b), (c), 0, 0, 0)

#define XASTR 136   // XA row stride (u16): mem[n] 128 + pad (node id at 128..129)
#define XBSTR 296   // XB row stride (u16): other(128)|ef(128)|te(16)|zero(16)
#define OSTR  132   // f32 output-stage row stride (XB reuse)
#define RSZ   (32 * XASTR + 32 * XBSTR)   // 13824 u16 = 27648 B per 32-node block

// -------- last_pos via atomicMax (== segment_max of positions) --------
__global__ void k_scatter(const int* __restrict__ src, const int* __restrict__ dst,
                          int* __restrict__ last_pos) {
    int i = blockIdx.x * blockDim.x + threadIdx.x;
    if (i < NE) {
        atomicMax(&last_pos[src[i]], i);
    } else if (i < 2 * NE) {
        atomicMax(&last_pos[dst[i - NE]], i);
    }
}

// -------- compact present nodes + resolve event info --------
__global__ void k_compact(const int* __restrict__ last_pos,
                          const int* __restrict__ src, const int* __restrict__ dst,
                          const float* __restrict__ ts, const float* __restrict__ lut,
                          int4* __restrict__ einfo, int* __restrict__ cnt) {
    int n = blockIdx.x * blockDim.x + threadIdx.x;
    if (n >= NN) return;
    int p = last_pos[n];
    if (p < 0) return;
    int e, other;
    if (p < NE) { e = p;      other = dst[e]; }
    else        { e = p - NE; other = src[e]; }
    float dt = ts[e] - lut[n];
    int idx = atomicAdd(cnt, 1);
    einfo[idx] = make_int4(n, e, other, __float_as_int(dt));
}

// -------- absent nodes: out = memory --------
__global__ void k_copy_absent(const float* __restrict__ mem, const int* __restrict__ last_pos,
                              float* __restrict__ out) {
    int t = blockIdx.x * blockDim.x + threadIdx.x;
    int node = t >> 5;
    if (node >= NN) return;
    if (last_pos[node] < 0) {
        int c = (t & 31) * 4;
        *(float4*)&out[(size_t)node * 128 + c] = *(const float4*)&mem[(size_t)node * 128 + c];
    }
}

// -------- weight prep: fp32 -> bf16, B-fragment-friendly [n][k] layouts --------
__global__ void k_prepw(const float* __restrict__ W1, const float* __restrict__ W2,
                        const float* __restrict__ Wih, const float* __restrict__ Whh,
                        ushort* __restrict__ W1T, ushort* __restrict__ W2T,
                        ushort* __restrict__ WI, ushort* __restrict__ WH) {
    int i = blockIdx.x * blockDim.x + threadIdx.x;
    if (i < 128 * 416) {
        int n = i / 416, k = i % 416;
        W1T[i] = (k < 400) ? f2b(W1[k * 128 + n]) : (ushort)0;
        return;
    }
    i -= 128 * 416;
    if (i < 128 * 128) { int n = i >> 7, k = i & 127; W2T[i] = f2b(W2[k * 128 + n]); return; }
    i -= 128 * 128;
    if (i < 384 * 128) { WI[i] = f2b(Wih[i]); return; }
    i -= 384 * 128;
    if (i < 384 * 128) { WH[i] = f2b(Whh[i]); }
}

// -------- gather: one wave per present node; writes packed LDS image to P --------
__global__ __launch_bounds__(256)
void k_gather(const int4* __restrict__ einfo, const int* __restrict__ cnt_p,
              const float* __restrict__ mem, const float* __restrict__ ef,
              const float* __restrict__ tw, const float* __restrict__ tphi,
              ushort* __restrict__ P)
{
    const int cnt = *cnt_p;
    const int R32 = (cnt + 31) & ~31;
    const int wv   = threadIdx.x >> 6;
    const int lane = threadIdx.x & 63;
    const int row  = blockIdx.x * 4 + wv;
    if (row >= R32) return;
    ushort* xa = P + (size_t)(row >> 5) * RSZ + (row & 31) * XASTR;
    ushort* xb = P + (size_t)(row >> 5) * RSZ + 32 * XASTR + (row & 31) * XBSTR;
    if (row < cnt) {
        int4 ei = einfo[row];
        int n = ei.x, e = ei.y, other = ei.z;
        float dtv = __int_as_float(ei.w);
        if (lane < 32) {
            float4 v = *(const float4*)&mem[(size_t)n * 128 + lane * 4];
            *(ushort4*)&xa[lane * 4] = cvt4(v);
            float4 w = *(const float4*)&ef[(size_t)e * 128 + lane * 4];
            *(ushort4*)&xb[128 + lane * 4] = cvt4(w);
            if (lane == 0) *(unsigned*)&xa[128] = (unsigned)n;
        } else {
            int l = lane - 32;
            float4 v = *(const float4*)&mem[(size_t)other * 128 + l * 4];
            *(ushort4*)&xb[l * 4] = cvt4(v);
            float val = 0.0f;
            if (l < 16) {
                float wt = fmaf(dtv, tw[l], tphi[l]);
                val = (l == 0) ? wt : sinf(wt);
            }
            xb[256 + l] = f2b(val);
        }
    } else {
        ushort4 z = {0, 0, 0, 0};
        if (lane < 32) {
            *(ushort4*)&xa[lane * 4] = z;
            *(ushort4*)&xb[128 + lane * 4] = z;
            if (lane == 0) *(unsigned*)&xa[128] = 0u;
        } else {
            int l = lane - 32;
            *(ushort4*)&xb[l * 4] = z;
            xb[256 + l] = 0;
        }
    }
}

// -------- main v2: stage packed P region via global_load_lds, then MFMA --------
__global__ __launch_bounds__(256, 4)
void k_main2(const ushort* __restrict__ P, const int* __restrict__ cnt_p,
             const ushort* __restrict__ W1T, const float* __restrict__ b1,
             const ushort* __restrict__ W2T, const float* __restrict__ b2,
             const ushort* __restrict__ WI, const ushort* __restrict__ WH,
             const float* __restrict__ bih, const float* __restrict__ bhh,
             float* __restrict__ out)
{
    __shared__ __align__(16) ushort LDS[RSZ];
    const int cnt  = *cnt_p;
    const int base = blockIdx.x * 32;
    if (base >= cnt) return;
    const int nt   = min(32, cnt - base);
    const int tid  = threadIdx.x;
    const int lane = tid & 63;
    const int wv   = tid >> 6;

    // ---- stage: 27 x 1KB coalesced chunks, direct global->LDS ----
    {
        const ushort* src = P + (size_t)blockIdx.x * RSZ;
        #pragma unroll
        for (int c = 0; c < 7; ++c) {
            int cc = wv + c * 4;
            if (cc < 27) gload_lds16(src + cc * 512 + lane * 8, &LDS[cc * 512]);
        }
    }
    __syncthreads();

    ushort* XA = LDS;
    ushort* XB = LDS + 32 * XASTR;

    const int r16 = lane & 15;
    const int kb  = lane >> 4;

    // ---- layer 1: h1 = relu(x @ W1 + b1), M=32 N=128 K=416 ----
    f32x4 c1[2][2] = {};
    {
        const ushort* aA = &XA[r16 * XASTR + kb * 8];
        const ushort* aB = &XB[r16 * XBSTR + kb * 8];
        const ushort* bp = &W1T[(size_t)(wv * 32 + r16) * 416 + kb * 8];
        #pragma unroll
        for (int kt = 0; kt < 13; ++kt) {
            const ushort* ap  = (kt < 4) ? (aA + kt * 32) : (aB + (kt - 4) * 32);
            const int     ast = (kt < 4) ? XASTR : XBSTR;
            bf16x8 A0 = *(const bf16x8*)ap;
            bf16x8 A1 = *(const bf16x8*)(ap + 16 * ast);
            bf16x8 B0 = *(const bf16x8*)(bp + kt * 32);
            bf16x8 B1 = *(const bf16x8*)(bp + 16 * 416 + kt * 32);
            c1[0][0] = MFMA16(A0, B0, c1[0][0]);
            c1[0][1] = MFMA16(A0, B1, c1[0][1]);
            c1[1][0] = MFMA16(A1, B0, c1[1][0]);
            c1[1][1] = MFMA16(A1, B1, c1[1][1]);
        }
    }
    __syncthreads();   // all XB reads done; safe to overwrite with H

    #pragma unroll
    for (int ns = 0; ns < 2; ++ns) {
        int col = wv * 32 + ns * 16 + r16;
        float bb = b1[col];
        #pragma unroll
        for (int m = 0; m < 2; ++m)
            #pragma unroll
            for (int r = 0; r < 4; ++r)
                XB[(m * 16 + kb * 4 + r) * XBSTR + col] = f2b(fmaxf(c1[m][ns][r] + bb, 0.0f));
    }
    __syncthreads();

    // ---- layer 2: msg = h1 @ W2 + b2, K=128; MSG -> disjoint XB cols ----
    f32x4 c2[2][2] = {};
    {
        const ushort* aA = &XB[r16 * XBSTR + kb * 8];
        const ushort* bp = &W2T[(size_t)(wv * 32 + r16) * 128 + kb * 8];
        #pragma unroll
        for (int kt = 0; kt < 4; ++kt) {
            bf16x8 A0 = *(const bf16x8*)(aA + kt * 32);
            bf16x8 A1 = *(const bf16x8*)(aA + 16 * XBSTR + kt * 32);
            bf16x8 B0 = *(const bf16x8*)(bp + kt * 32);
            bf16x8 B1 = *(const bf16x8*)(bp + 16 * 128 + kt * 32);
            c2[0][0] = MFMA16(A0, B0, c2[0][0]);
            c2[0][1] = MFMA16(A0, B1, c2[0][1]);
            c2[1][0] = MFMA16(A1, B0, c2[1][0]);
            c2[1][1] = MFMA16(A1, B1, c2[1][1]);
        }
    }
    #pragma unroll
    for (int ns = 0; ns < 2; ++ns) {
        int col = wv * 32 + ns * 16 + r16;
        float bb = b2[col];
        #pragma unroll
        for (int m = 0; m < 2; ++m)
            #pragma unroll
            for (int r = 0; r < 4; ++r)
                XB[(m * 16 + kb * 4 + r) * XBSTR + 136 + col] = f2b(c2[m][ns][r] + bb);
    }
    __syncthreads();

    // ---- GRU ----
    f32x4 arz[2][4] = {};
    f32x4 an_i[2][2] = {};
    f32x4 an_h[2][2] = {};
    {
        const ushort* am = &XB[r16 * XBSTR + 136 + kb * 8];
        const ushort* ah = &XA[r16 * XASTR + kb * 8];
        const size_t cb = (size_t)(wv * 32 + r16) * 128 + kb * 8;
        const ushort* bi = WI + cb;
        const ushort* bh = WH + cb;
        #pragma unroll
        for (int kt = 0; kt < 4; ++kt) {
            bf16x8 M0 = *(const bf16x8*)(am + kt * 32);
            bf16x8 M1 = *(const bf16x8*)(am + 16 * XBSTR + kt * 32);
            bf16x8 H0 = *(const bf16x8*)(ah + kt * 32);
            bf16x8 H1 = *(const bf16x8*)(ah + 16 * XASTR + kt * 32);
            #pragma unroll
            for (int g = 0; g < 2; ++g)
                #pragma unroll
                for (int ns = 0; ns < 2; ++ns) {
                    size_t off = (size_t)(g * 128 + ns * 16) * 128 + kt * 32;
                    bf16x8 Bi = *(const bf16x8*)(bi + off);
                    bf16x8 Bh = *(const bf16x8*)(bh + off);
                    arz[0][g * 2 + ns] = MFMA16(M0, Bi, arz[0][g * 2 + ns]);
                    arz[0][g * 2 + ns] = MFMA16(H0, Bh, arz[0][g * 2 + ns]);
                    arz[1][g * 2 + ns] = MFMA16(M1, Bi, arz[1][g * 2 + ns]);
                    arz[1][g * 2 + ns] = MFMA16(H1, Bh, arz[1][g * 2 + ns]);
                }
            #pragma unroll
            for (int ns = 0; ns < 2; ++ns) {
                size_t off = (size_t)(256 + ns * 16) * 128 + kt * 32;
                bf16x8 Bi = *(const bf16x8*)(bi + off);
                bf16x8 Bh = *(const bf16x8*)(bh + off);
                an_i[0][ns] = MFMA16(M0, Bi, an_i[0][ns]);
                an_i[1][ns] = MFMA16(M1, Bi, an_i[1][ns]);
                an_h[0][ns] = MFMA16(H0, Bh, an_h[0][ns]);
                an_h[1][ns] = MFMA16(H1, Bh, an_h[1][ns]);
            }
        }
    }
    __syncthreads();   // MSG reads done; XB reusable as f32 out-stage

    // ---- epilogue: gates + blend -> f32 stage in LDS ----
    float* XBf = (float*)XB;
    #pragma unroll
    for (int ns = 0; ns < 2; ++ns) {
        int col = wv * 32 + ns * 16 + r16;
        float brz0 = bih[col] + bhh[col];
        float brz1 = bih[128 + col] + bhh[128 + col];
        float bin  = bih[256 + col];
        float bhn  = bhh[256 + col];
        #pragma unroll
        for (int m = 0; m < 2; ++m) {
            #pragma unroll
            for (int r = 0; r < 4; ++r) {
                int row = m * 16 + kb * 4 + r;
                float rr = sigm(arz[m][0 + ns][r] + brz0);
                float zz = sigm(arz[m][2 + ns][r] + brz1);
                float nn = tanhf(an_i[m][ns][r] + bin + rr * (an_h[m][ns][r] + bhn));
                float hh = b2f(XA[row * XASTR + col]);
                XBf[row * OSTR + col] = (1.0f - zz) * nn + zz * hh;
            }
        }
    }
    __syncthreads();

    // ---- coalesced store: one wave writes a full 512 B row ----
    for (int j = wv; j < nt; j += 4) {
        unsigned node = *(const unsigned*)&XA[j * XASTR + 128];
        float2 v = *(const float2*)&XBf[j * OSTR + lane * 2];
        *(float2*)&out[(size_t)node * 128 + lane * 2] = v;
    }
}

// -------- fallback main (round-4 path, used if ws too small for P) --------
__global__ __launch_bounds__(256, 4)
void k_main(const int4* __restrict__ einfo, const int* __restrict__ cnt_p,
            const float* __restrict__ ef,
            const float* __restrict__ mem,
            const float* __restrict__ tw, const float* __restrict__ tphi,
            const ushort* __restrict__ W1T, const float* __restrict__ b1,
            const ushort* __restrict__ W2T, const float* __restrict__ b2,
            const ushort* __restrict__ WI, const ushort* __restrict__ WH,
            const float* __restrict__ bih, const float* __restrict__ bhh,
            float* __restrict__ out)
{
    __shared__ __align__(16) ushort XA[32 * XASTR];
    __shared__ __align__(16) ushort XB[32 * XBSTR];
    __shared__ int snode[32];

    const int cnt  = *cnt_p;
    const int base = blockIdx.x * 32;
    if (base >= cnt) return;
    const int nt   = min(32, cnt - base);
    const int tid  = threadIdx.x;
    const int lane = tid & 63;
    const int wv   = tid >> 6;

    {
        int4 ei[8];
        #pragma unroll
        for (int j = 0; j < 8; ++j) {
            int i = wv + j * 4;
            ei[j] = einfo[base + min(i, nt - 1)];
        }
        #pragma unroll
        for (int j = 0; j < 8; ++j) {
            int i = wv + j * 4;
            int n = ei[j].x, e = ei[j].y, other = ei[j].z;
            float dtv = __int_as_float(ei[j].w);
            if (lane == 0) snode[i] = n;
            if (lane < 32) {
                float4 v = *(const float4*)&mem[(size_t)n * 128 + lane * 4];
                *(ushort4*)&XA[i * XASTR + lane * 4] = cvt4(v);
                float4 w = *(const float4*)&ef[(size_t)e * 128 + lane * 4];
                *(ushort4*)&XB[i * XBSTR + 128 + lane * 4] = cvt4(w);
            } else {
                int l = lane - 32;
                float4 v = *(const float4*)&mem[(size_t)other * 128 + l * 4];
                *(ushort4*)&XB[i * XBSTR + l * 4] = cvt4(v);
                float val = 0.0f;
                if (l < 16) {
                    float wt = fmaf(dtv, tw[l], tphi[l]);
                    val = (l == 0) ? wt : sinf(wt);
                }
                XB[i * XBSTR + 256 + l] = f2b(val);
            }
        }
    }
    __syncthreads();

    const int r16 = lane & 15;
    const int kb  = lane >> 4;

    f32x4 c1[2][2] = {};
    {
        const ushort* aA = &XA[r16 * XASTR + kb * 8];
        const ushort* aB = &XB[r16 * XBSTR + kb * 8];
        const ushort* bp = &W1T[(size_t)(wv * 32 + r16) * 416 + kb * 8];
        #pragma unroll
        for (int kt = 0; kt < 13; ++kt) {
            const ushort* ap  = (kt < 4) ? (aA + kt * 32) : (aB + (kt - 4) * 32);
            const int     ast = (kt < 4) ? XASTR : XBSTR;
            bf16x8 A0 = *(const bf16x8*)ap;
            bf16x8 A1 = *(const bf16x8*)(ap + 16 * ast);
            bf16x8 B0 = *(const bf16x8*)(bp + kt * 32);
            bf16x8 B1 = *(const bf16x8*)(bp + 16 * 416 + kt * 32);
            c1[0][0] = MFMA16(A0, B0, c1[0][0]);
            c1[0][1] = MFMA16(A0, B1, c1[0][1]);
            c1[1][0] = MFMA16(A1, B0, c1[1][0]);
            c1[1][1] = MFMA16(A1, B1, c1[1][1]);
        }
    }
    __syncthreads();

    #pragma unroll
    for (int ns = 0; ns < 2; ++ns) {
        int col = wv * 32 + ns * 16 + r16;
        float bb = b1[col];
        #pragma unroll
        for (int m = 0; m < 2; ++m)
            #pragma unroll
            for (int r = 0; r < 4; ++r)
                XB[(m * 16 + kb * 4 + r) * XBSTR + col] = f2b(fmaxf(c1[m][ns][r] + bb, 0.0f));
    }
    __syncthreads();

    f32x4 c2[2][2] = {};
    {
        const ushort* aA = &XB[r16 * XBSTR + kb * 8];
        const ushort* bp = &W2T[(size_t)(wv * 32 + r16) * 128 + kb * 8];
        #pragma unroll
        for (int kt = 0; kt < 4; ++kt) {
            bf16x8 A0 = *(const bf16x8*)(aA + kt * 32);
            bf16x8 A1 = *(const bf16x8*)(aA + 16 * XBSTR + kt * 32);
            bf16x8 B0 = *(const bf16x8*)(bp + kt * 32);
            bf16x8 B1 = *(const bf16x8*)(bp + 16 * 128 + kt * 32);
            c2[0][0] = MFMA16(A0, B0, c2[0][0]);
            c2[0][1] = MFMA16(A0, B1, c2[0][1]);
            c2[1][0] = MFMA16(A1, B0, c2[1][0]);
            c2[1][1] = MFMA16(A1, B1, c2[1][1]);
        }
    }
    #pragma unroll
    for (int ns = 0; ns < 2; ++ns) {
        int col = wv * 32 + ns * 16 + r16;
        float bb = b2[col];
        #pragma unroll
        for (int m = 0; m < 2; ++m)
            #pragma unroll
            for (int r = 0; r < 4; ++r)
                XB[(m * 16 + kb * 4 + r) * XBSTR + 136 + col] = f2b(c2[m][ns][r] + bb);
    }
    __syncthreads();

    f32x4 arz[2][4] = {};
    f32x4 an_i[2][2] = {};
    f32x4 an_h[2][2] = {};
    {
        const ushort* am = &XB[r16 * XBSTR + 136 + kb * 8];
        const ushort* ah = &XA[r16 * XASTR + kb * 8];
        const size_t cb = (size_t)(wv * 32 + r16) * 128 + kb * 8;
        const ushort* bi = WI + cb;
        const ushort* bh = WH + cb;
        #pragma unroll
        for (int kt = 0; kt < 4; ++kt) {
            bf16x8 M0 = *(const bf16x8*)(am + kt * 32);
            bf16x8 M1 = *(const bf16x8*)(am + 16 * XBSTR + kt * 32);
            bf16x8 H0 = *(const bf16x8*)(ah + kt * 32);
            bf16x8 H1 = *(const bf16x8*)(ah + 16 * XASTR + kt * 32);
            #pragma unroll
            for (int g = 0; g < 2; ++g)
                #pragma unroll
                for (int ns = 0; ns < 2; ++ns) {
                    size_t off = (size_t)(g * 128 + ns * 16) * 128 + kt * 32;
                    bf16x8 Bi = *(const bf16x8*)(bi + off);
                    bf16x8 Bh = *(const bf16x8*)(bh + off);
                    arz[0][g * 2 + ns] = MFMA16(M0, Bi, arz[0][g * 2 + ns]);
                    arz[0][g * 2 + ns] = MFMA16(H0, Bh, arz[0][g * 2 + ns]);
                    arz[1][g * 2 + ns] = MFMA16(M1, Bi, arz[1][g * 2 + ns]);
                    arz[1][g * 2 + ns] = MFMA16(H1, Bh, arz[1][g * 2 + ns]);
                }
            #pragma unroll
            for (int ns = 0; ns < 2; ++ns) {
                size_t off = (size_t)(256 + ns * 16) * 128 + kt * 32;
                bf16x8 Bi = *(const bf16x8*)(bi + off);
                bf16x8 Bh = *(const bf16x8*)(bh + off);
                an_i[0][ns] = MFMA16(M0, Bi, an_i[0][ns]);
                an_i[1][ns] = MFMA16(M1, Bi, an_i[1][ns]);
                an_h[0][ns] = MFMA16(H0, Bh, an_h[0][ns]);
                an_h[1][ns] = MFMA16(H1, Bh, an_h[1][ns]);
            }
        }
    }
    __syncthreads();

    float* XBf = (float*)XB;
    #pragma unroll
    for (int ns = 0; ns < 2; ++ns) {
        int col = wv * 32 + ns * 16 + r16;
        float brz0 = bih[col] + bhh[col];
        float brz1 = bih[128 + col] + bhh[128 + col];
        float bin  = bih[256 + col];
        float bhn  = bhh[256 + col];
        #pragma unroll
        for (int m = 0; m < 2; ++m) {
            #pragma unroll
            for (int r = 0; r < 4; ++r) {
                int row = m * 16 + kb * 4 + r;
                float rr = sigm(arz[m][0 + ns][r] + brz0);
                float zz = sigm(arz[m][2 + ns][r] + brz1);
                float nn = tanhf(an_i[m][ns][r] + bin + rr * (an_h[m][ns][r] + bhn));
                float hh = b2f(XA[row * XASTR + col]);
                XBf[row * OSTR + col] = (1.0f - zz) * nn + zz * hh;
            }
        }
    }
    __syncthreads();

    for (int j = wv; j < nt; j += 4) {
        float2 v = *(const float2*)&XBf[j * OSTR + lane * 2];
        *(float2*)&out[(size_t)snode[j] * 128 + lane * 2] = v;
    }
}

extern "C" void kernel_launch(void* const* d_in, const int* in_sizes, int n_in,
                              void* d_out, int out_size, void* d_ws, size_t ws_size,
                              hipStream_t stream) {
    const int*   src  = (const int*)d_in[0];
    const int*   dst  = (const int*)d_in[1];
    const float* ef   = (const float*)d_in[2];
    const float* ts   = (const float*)d_in[3];
    const float* mem  = (const float*)d_in[4];
    const float* lut  = (const float*)d_in[5];
    const float* tw   = (const float*)d_in[6];
    const float* tphi = (const float*)d_in[7];
    const float* W1   = (const float*)d_in[8];
    const float* b1   = (const float*)d_in[9];
    const float* W2   = (const float*)d_in[10];
    const float* b2   = (const float*)d_in[11];
    const float* Wih  = (const float*)d_in[12];
    const float* Whh  = (const float*)d_in[13];
    const float* bih  = (const float*)d_in[14];
    const float* bhh  = (const float*)d_in[15];
    float* out = (float*)d_out;

    char* ws = (char*)d_ws;
    size_t off = 0;
    int*    last_pos = (int*)(ws + off);  off += (size_t)NN * 4;
    int4*   einfo    = (int4*)(ws + off); off += (size_t)NN * 16;
    int*    cnt      = (int*)(ws + off);  off += 16;
    ushort* W1T      = (ushort*)(ws + off); off += (size_t)128 * 416 * 2;
    ushort* W2T      = (ushort*)(ws + off); off += (size_t)128 * 128 * 2;
    ushort* WI       = (ushort*)(ws + off); off += (size_t)384 * 128 * 2;
    ushort* WH       = (ushort*)(ws + off); off += (size_t)384 * 128 * 2;
    ushort* P        = (ushort*)(ws + off);
    const size_t needed = off + (size_t)((NN + 31) / 32) * RSZ * 2;
    const bool two_pass = (ws_size >= needed);

    hipMemsetAsync(last_pos, 0xFF, (size_t)NN * sizeof(int), stream);  // -1
    hipMemsetAsync(cnt, 0, sizeof(int), stream);

    k_prepw<<<(128 * 416 + 128 * 128 + 2 * 384 * 128 + 255) / 256, 256, 0, stream>>>(
        W1, W2, Wih, Whh, W1T, W2T, WI, WH);
    k_scatter<<<(2 * NE + 255) / 256, 256, 0, stream>>>(src, dst, last_pos);
    k_compact<<<(NN + 255) / 256, 256, 0, stream>>>(last_pos, src, dst, ts, lut, einfo, cnt);
    k_copy_absent<<<(NN * 32 + 255) / 256, 256, 0, stream>>>(mem, last_pos, out);

    if (two_pass) {
        k_gather<<<(NN + 3) / 4, 256, 0, stream>>>(einfo, cnt, mem, ef, tw, tphi, P);
        k_main2<<<(NN + 31) / 32, 256, 0, stream>>>(P, cnt, W1T, b1, W2T, b2,
                                                    WI, WH, bih, bhh, out);
    } else {
        k_main<<<(NN + 31) / 32, 256, 0, stream>>>(einfo, cnt, ef, mem, tw, tphi,
                                                   W1T, b1, W2T, b2, WI, WH, bih, bhh, out);
    }
}

// Round 6
// 329.212 us; speedup vs baseline: 1.2660x; 1.2660x over previous
//
#include <hip/hip_runtime.h>
#include <hip/hip_bf16.h>
#include <math.h>

#define NN 200000
#define NE 200000

typedef __attribute__((ext_vector_type(8))) short bf16x8;
typedef __attribute__((ext_vector_type(4))) float f32x4;

__device__ __forceinline__ float sigm(float x) { return 1.0f / (1.0f + expf(-x)); }

__device__ __forceinline__ ushort f2b(float x) {
    union { __hip_bfloat16 b; ushort u; } v;
    v.b = __float2bfloat16(x);
    return v.u;
}
__device__ __forceinline__ float b2f(ushort u) {
    return __uint_as_float(((unsigned)u) << 16);
}
__device__ __forceinline__ ushort4 cvt4(float4 v) {
    ushort4 u; u.x = f2b(v.x); u.y = f2b(v.y); u.z = f2b(v.z); u.w = f2b(v.w);
    return u;
}
__device__ __forceinline__ void gload_lds16(const ushort* g, ushort* l) {
    __builtin_amdgcn_global_load_lds(
        (const __attribute__((address_space(1))) unsigned int*)g,
        (__attribute__((address_space(3))) unsigned int*)l, 16, 0, 0);
}

#define MFMA16(a, b, c) __builtin_amdgcn_mfma_f32_16x16x32_bf16((a), (b), (c), 0, 0, 0)

#define XASTR 136   // XA row stride (u16): mem[n] 128 + node id at [128..129]
#define XBSTR 296   // XB row stride (u16): other(128)|ef(128)|te(16)|zero(16)
#define OSTR  132   // f32 output-stage row stride (XB reuse)
#define RSZ   (32 * XASTR + 32 * XBSTR)   // 13824 u16 = 27648 B per 32-node block

// -------- last_pos via atomicMax (== segment_max of positions) --------
__global__ void k_scatter(const int* __restrict__ src, const int* __restrict__ dst,
                          int* __restrict__ last_pos) {
    int i = blockIdx.x * blockDim.x + threadIdx.x;
    if (i < NE) {
        atomicMax(&last_pos[src[i]], i);
    } else if (i < 2 * NE) {
        atomicMax(&last_pos[dst[i - NE]], i);
    }
}

// -------- compact present nodes + resolve event info --------
__global__ void k_compact(const int* __restrict__ last_pos,
                          const int* __restrict__ src, const int* __restrict__ dst,
                          const float* __restrict__ ts, const float* __restrict__ lut,
                          int4* __restrict__ einfo, int* __restrict__ cnt) {
    int n = blockIdx.x * blockDim.x + threadIdx.x;
    if (n >= NN) return;
    int p = last_pos[n];
    if (p < 0) return;
    int e, other;
    if (p < NE) { e = p;      other = dst[e]; }
    else        { e = p - NE; other = src[e]; }
    float dt = ts[e] - lut[n];
    int idx = atomicAdd(cnt, 1);
    einfo[idx] = make_int4(n, e, other, __float_as_int(dt));
}

// -------- absent nodes: out = memory --------
__global__ void k_copy_absent(const float* __restrict__ mem, const int* __restrict__ last_pos,
                              float* __restrict__ out) {
    int t = blockIdx.x * blockDim.x + threadIdx.x;
    int node = t >> 5;
    if (node >= NN) return;
    if (last_pos[node] < 0) {
        int c = (t & 31) * 4;
        *(float4*)&out[(size_t)node * 128 + c] = *(const float4*)&mem[(size_t)node * 128 + c];
    }
}

// -------- compose: CW[col][j] = sum_k W2[j][k]*Wih[col][k];  cb = b2@WI^T + bih --------
__global__ void k_compose(const float* __restrict__ W2, const float* __restrict__ Wih,
                          const float* __restrict__ b2, const float* __restrict__ bih,
                          float* __restrict__ CW, float* __restrict__ cb) {
    int i = blockIdx.x * blockDim.x + threadIdx.x;
    if (i < 384 * 128) {
        int col = i >> 7, j = i & 127;
        float s = 0.0f;
        for (int k = 0; k < 128; ++k) s = fmaf(W2[j * 128 + k], Wih[col * 128 + k], s);
        CW[i] = s;
    }
    if (i < 384) {
        float s = bih[i];
        for (int k = 0; k < 128; ++k) s = fmaf(b2[k], Wih[i * 128 + k], s);
        cb[i] = s;
    }
}

// -------- pack weights into fragment-linear bf16 buffers --------
// W1F : 104 frags (wave wv: 26 frags = kt 0..12 x ns 0..1)
// W2IF: 96 frags  (wave wv: 24 frags = kt 0..3 x g 0..2 x ns 0..1)  from CW
// WHF : 96 frags  same enumeration, from Whh
// frag layout: frag f, lane l, elem j -> [f*512 + l*8 + j]; element = W[col][k]
//   col = gatebase + wv*32 + ns*16 + (l&15),  k = kt*32 + (l>>4)*8 + j
__global__ void k_prepfrag(const float* __restrict__ W1, const float* __restrict__ CW,
                           const float* __restrict__ Whh,
                           ushort* __restrict__ W1F, ushort* __restrict__ W2IF,
                           ushort* __restrict__ WHF) {
    int t = blockIdx.x * blockDim.x + threadIdx.x;
    int f = t >> 9;
    int idx = t & 511;
    int lane = idx >> 3, j = idx & 7;
    int c16 = lane & 15, k8 = lane >> 4;
    if (f < 104) {
        int wv = f / 26, r = f % 26;
        int kt = r >> 1, ns = r & 1;
        int col = wv * 32 + ns * 16 + c16;
        int kk = kt * 32 + k8 * 8 + j;
        W1F[t] = (kk < 400) ? f2b(W1[kk * 128 + col]) : (ushort)0;   // W1 is [400][128]
        return;
    }
    f -= 104;
    if (f < 96) {
        int wv = f / 24, r = f % 24;
        int kt = r / 6, rem = r % 6, g = rem >> 1, ns = rem & 1;
        int col = g * 128 + wv * 32 + ns * 16 + c16;
        int kk = kt * 32 + k8 * 8 + j;
        W2IF[f * 512 + idx] = f2b(CW[col * 128 + kk]);
        return;
    }
    f -= 96;
    if (f < 96) {
        int wv = f / 24, r = f % 24;
        int kt = r / 6, rem = r % 6, g = rem >> 1, ns = rem & 1;
        int col = g * 128 + wv * 32 + ns * 16 + c16;
        int kk = kt * 32 + k8 * 8 + j;
        WHF[f * 512 + idx] = f2b(Whh[col * 128 + kk]);
    }
}

// -------- gather: one wave per present node; writes packed LDS image to P --------
__global__ __launch_bounds__(256)
void k_gather(const int4* __restrict__ einfo, const int* __restrict__ cnt_p,
              const float* __restrict__ mem, const float* __restrict__ ef,
              const float* __restrict__ tw, const float* __restrict__ tphi,
              ushort* __restrict__ P)
{
    const int cnt = *cnt_p;
    const int R32 = (cnt + 31) & ~31;
    const int wv   = threadIdx.x >> 6;
    const int lane = threadIdx.x & 63;
    const int row  = blockIdx.x * 4 + wv;
    if (row >= R32) return;
    ushort* xa = P + (size_t)(row >> 5) * RSZ + (row & 31) * XASTR;
    ushort* xb = P + (size_t)(row >> 5) * RSZ + 32 * XASTR + (row & 31) * XBSTR;
    if (row < cnt) {
        int4 ei = einfo[row];
        int n = ei.x, e = ei.y, other = ei.z;
        float dtv = __int_as_float(ei.w);
        if (lane < 32) {
            float4 v = *(const float4*)&mem[(size_t)n * 128 + lane * 4];
            *(ushort4*)&xa[lane * 4] = cvt4(v);
            float4 w = *(const float4*)&ef[(size_t)e * 128 + lane * 4];
            *(ushort4*)&xb[128 + lane * 4] = cvt4(w);
            if (lane == 0) *(unsigned*)&xa[128] = (unsigned)n;
        } else {
            int l = lane - 32;
            float4 v = *(const float4*)&mem[(size_t)other * 128 + l * 4];
            *(ushort4*)&xb[l * 4] = cvt4(v);
            float val = 0.0f;
            if (l < 16) {
                float wt = fmaf(dtv, tw[l], tphi[l]);
                val = (l == 0) ? wt : sinf(wt);
            }
            xb[256 + l] = f2b(val);
        }
    } else {
        ushort4 z = {0, 0, 0, 0};
        if (lane < 32) {
            *(ushort4*)&xa[lane * 4] = z;
            *(ushort4*)&xb[128 + lane * 4] = z;
            if (lane == 0) *(unsigned*)&xa[128] = 0u;
        } else {
            int l = lane - 32;
            *(ushort4*)&xb[l * 4] = z;
            xb[256 + l] = 0;
        }
    }
}

// -------- main v3: staged P + fragment-linear weights + composed GRU --------
__global__ __launch_bounds__(256, 4)
void k_main3(const ushort* __restrict__ P, const int* __restrict__ cnt_p,
             const ushort* __restrict__ W1F, const float* __restrict__ b1,
             const ushort* __restrict__ W2IF, const ushort* __restrict__ WHF,
             const float* __restrict__ cb, const float* __restrict__ bhh,
             float* __restrict__ out)
{
    __shared__ __align__(16) ushort LDS[RSZ];
    const int cnt  = *cnt_p;
    const int base = blockIdx.x * 32;
    if (base >= cnt) return;
    const int nt   = min(32, cnt - base);
    const int tid  = threadIdx.x;
    const int lane = tid & 63;
    const int wv   = tid >> 6;

    // ---- stage: 27 x 1KB coalesced chunks, direct global->LDS ----
    {
        const ushort* src = P + (size_t)blockIdx.x * RSZ;
        #pragma unroll
        for (int c = 0; c < 7; ++c) {
            int cc = wv + c * 4;
            if (cc < 27) gload_lds16(src + cc * 512 + lane * 8, &LDS[cc * 512]);
        }
    }
    __syncthreads();

    ushort* XA = LDS;
    ushort* XB = LDS + 32 * XASTR;

    const int r16 = lane & 15;
    const int kb  = lane >> 4;

    // ---- layer 1: h1 = relu(x @ W1 + b1), M=32 N=128 K=416 ----
    f32x4 c1[2][2] = {};
    {
        const ushort* aA = &XA[r16 * XASTR + kb * 8];
        const ushort* aB = &XB[r16 * XBSTR + kb * 8];
        const ushort* w1 = W1F + wv * (26 * 512) + lane * 8;
        #pragma unroll
        for (int kt = 0; kt < 13; ++kt) {
            const ushort* ap  = (kt < 4) ? (aA + kt * 32) : (aB + (kt - 4) * 32);
            const int     ast = (kt < 4) ? XASTR : XBSTR;
            bf16x8 A0 = *(const bf16x8*)ap;
            bf16x8 A1 = *(const bf16x8*)(ap + 16 * ast);
            bf16x8 B0 = *(const bf16x8*)(w1 + (kt * 2 + 0) * 512);
            bf16x8 B1 = *(const bf16x8*)(w1 + (kt * 2 + 1) * 512);
            c1[0][0] = MFMA16(A0, B0, c1[0][0]);
            c1[0][1] = MFMA16(A0, B1, c1[0][1]);
            c1[1][0] = MFMA16(A1, B0, c1[1][0]);
            c1[1][1] = MFMA16(A1, B1, c1[1][1]);
        }
    }
    __syncthreads();   // all X reads done; safe to overwrite XB cols 0..127 with H

    #pragma unroll
    for (int ns = 0; ns < 2; ++ns) {
        int col = wv * 32 + ns * 16 + r16;
        float bb = b1[col];
        #pragma unroll
        for (int m = 0; m < 2; ++m)
            #pragma unroll
            for (int r = 0; r < 4; ++r)
                XB[(m * 16 + kb * 4 + r) * XBSTR + col] = f2b(fmaxf(c1[m][ns][r] + bb, 0.0f));
    }
    __syncthreads();

    // ---- GRU (composed): gi = h1 @ CW^T-frags, gh = h @ WH-frags ----
    f32x4 arz[2][4] = {};    // [m][g*2+ns], g in {r,z}; gi+gh summed in-place
    f32x4 an_i[2][2] = {};
    f32x4 an_h[2][2] = {};
    {
        const ushort* am = &XB[r16 * XBSTR + kb * 8];   // h1 (H overlay)
        const ushort* ah = &XA[r16 * XASTR + kb * 8];   // h = mem[n]
        const ushort* wI = W2IF + wv * (24 * 512) + lane * 8;
        const ushort* wH = WHF  + wv * (24 * 512) + lane * 8;
        #pragma unroll
        for (int kt = 0; kt < 4; ++kt) {
            bf16x8 M0 = *(const bf16x8*)(am + kt * 32);
            bf16x8 M1 = *(const bf16x8*)(am + 16 * XBSTR + kt * 32);
            bf16x8 H0 = *(const bf16x8*)(ah + kt * 32);
            bf16x8 H1 = *(const bf16x8*)(ah + 16 * XASTR + kt * 32);
            #pragma unroll
            for (int g = 0; g < 2; ++g)
                #pragma unroll
                for (int ns = 0; ns < 2; ++ns) {
                    int fo = (kt * 6 + g * 2 + ns) * 512;
                    bf16x8 Bi = *(const bf16x8*)(wI + fo);
                    bf16x8 Bh = *(const bf16x8*)(wH + fo);
                    arz[0][g * 2 + ns] = MFMA16(M0, Bi, arz[0][g * 2 + ns]);
                    arz[0][g * 2 + ns] = MFMA16(H0, Bh, arz[0][g * 2 + ns]);
                    arz[1][g * 2 + ns] = MFMA16(M1, Bi, arz[1][g * 2 + ns]);
                    arz[1][g * 2 + ns] = MFMA16(H1, Bh, arz[1][g * 2 + ns]);
                }
            #pragma unroll
            for (int ns = 0; ns < 2; ++ns) {
                int fo = (kt * 6 + 4 + ns) * 512;
                bf16x8 Bi = *(const bf16x8*)(wI + fo);
                bf16x8 Bh = *(const bf16x8*)(wH + fo);
                an_i[0][ns] = MFMA16(M0, Bi, an_i[0][ns]);
                an_i[1][ns] = MFMA16(M1, Bi, an_i[1][ns]);
                an_h[0][ns] = MFMA16(H0, Bh, an_h[0][ns]);
                an_h[1][ns] = MFMA16(H1, Bh, an_h[1][ns]);
            }
        }
    }
    __syncthreads();   // H/h reads done; XB reusable as f32 out-stage

    // ---- epilogue: gates + blend -> f32 stage in LDS ----
    float* XBf = (float*)XB;
    #pragma unroll
    for (int ns = 0; ns < 2; ++ns) {
        int col = wv * 32 + ns * 16 + r16;
        float brz0 = cb[col] + bhh[col];
        float brz1 = cb[128 + col] + bhh[128 + col];
        float bin  = cb[256 + col];
        float bhn  = bhh[256 + col];
        #pragma unroll
        for (int m = 0; m < 2; ++m) {
            #pragma unroll
            for (int r = 0; r < 4; ++r) {
                int row = m * 16 + kb * 4 + r;
                float rr = sigm(arz[m][0 + ns][r] + brz0);
                float zz = sigm(arz[m][2 + ns][r] + brz1);
                float nn = tanhf(an_i[m][ns][r] + bin + rr * (an_h[m][ns][r] + bhn));
                float hh = b2f(XA[row * XASTR + col]);
                XBf[row * OSTR + col] = (1.0f - zz) * nn + zz * hh;
            }
        }
    }
    __syncthreads();

    // ---- coalesced store: one wave writes a full 512 B row ----
    for (int j = wv; j < nt; j += 4) {
        unsigned node = *(const unsigned*)&XA[j * XASTR + 128];
        float2 v = *(const float2*)&XBf[j * OSTR + lane * 2];
        *(float2*)&out[(size_t)node * 128 + lane * 2] = v;
    }
}

extern "C" void kernel_launch(void* const* d_in, const int* in_sizes, int n_in,
                              void* d_out, int out_size, void* d_ws, size_t ws_size,
                              hipStream_t stream) {
    const int*   src  = (const int*)d_in[0];
    const int*   dst  = (const int*)d_in[1];
    const float* ef   = (const float*)d_in[2];
    const float* ts   = (const float*)d_in[3];
    const float* mem  = (const float*)d_in[4];
    const float* lut  = (const float*)d_in[5];
    const float* tw   = (const float*)d_in[6];
    const float* tphi = (const float*)d_in[7];
    const float* W1   = (const float*)d_in[8];
    const float* b1   = (const float*)d_in[9];
    const float* W2   = (const float*)d_in[10];
    const float* b2   = (const float*)d_in[11];
    const float* Wih  = (const float*)d_in[12];
    const float* Whh  = (const float*)d_in[13];
    const float* bih  = (const float*)d_in[14];
    const float* bhh  = (const float*)d_in[15];
    float* out = (float*)d_out;

    char* ws = (char*)d_ws;
    size_t off = 0;
    int*    last_pos = (int*)(ws + off);    off += (size_t)NN * 4;
    int4*   einfo    = (int4*)(ws + off);   off += (size_t)NN * 16;
    int*    cnt      = (int*)(ws + off);    off += 16;
    float*  CW       = (float*)(ws + off);  off += (size_t)384 * 128 * 4;
    float*  cb       = (float*)(ws + off);  off += (size_t)384 * 4 + 16;
    ushort* W1F      = (ushort*)(ws + off); off += (size_t)104 * 512 * 2;
    ushort* W2IF     = (ushort*)(ws + off); off += (size_t)96 * 512 * 2;
    ushort* WHF      = (ushort*)(ws + off); off += (size_t)96 * 512 * 2;
    ushort* P        = (ushort*)(ws + off);

    hipMemsetAsync(last_pos, 0xFF, (size_t)NN * sizeof(int), stream);  // -1
    hipMemsetAsync(cnt, 0, sizeof(int), stream);

    k_compose<<<(384 * 128 + 255) / 256, 256, 0, stream>>>(W2, Wih, b2, bih, CW, cb);
    k_prepfrag<<<((104 + 96 + 96) * 512 + 255) / 256, 256, 0, stream>>>(
        W1, CW, Whh, W1F, W2IF, WHF);
    k_scatter<<<(2 * NE + 255) / 256, 256, 0, stream>>>(src, dst, last_pos);
    k_compact<<<(NN + 255) / 256, 256, 0, stream>>>(last_pos, src, dst, ts, lut, einfo, cnt);
    k_copy_absent<<<(NN * 32 + 255) / 256, 256, 0, stream>>>(mem, last_pos, out);
    k_gather<<<(NN + 3) / 4, 256, 0, stream>>>(einfo, cnt, mem, ef, tw, tphi, P);
    k_main3<<<(NN + 31) / 32, 256, 0, stream>>>(P, cnt, W1F, b1, W2IF, WHF, cb, bhh, out);
}